// Round 9
// baseline (745.232 us; speedup 1.0000x reference)
//
#include <hip/hip_runtime.h>

// BilinearAttention B=8, N=2048, H=1024 — MFMA f16-split pipeline, v10:
// v9 sync skeleton, MFMA shape switched 16x16x32 -> 32x32x16 (measured
// +17-20% MFMA ceiling: 2382-2495 TF vs 2075-2176, m06/m119) and half the
// MFMA instruction count. Cohort rotation dropped (proven null twice).
//
// Global plane-grouped format: rows of 128-byte groups; group g covers
// k=[g*32,g*32+32) as [32 hi f16 | 32 lo f16] (split) or k=[g*64,g*64+64)
// as [64 f16] (plain). Row stride 4096 B, 32 k-groups everywhere.
// A 32-half k-group = two K=16 fragments at byte offset s*32+(lane>>5)*16;
// swizzle fields stay bit-disjoint so the XOR involution is unchanged.
//
//   prep_v : value fp32 -> Vp planes + Vt f16 [b][h][n]
//   prep_w : W fp32 [k][n] -> Wtp planes [n][g][hi|lo]
//   prep_q : query fp32 -> Qp planes (parked in attn region)
//   gemm1_qw : interP = split(Qp) @ Wtp  -> planes in out region
//   gemm2_av : logits = relu(interP @ Vp^T) masked -> attn fp32
//   softmax2048 : rowwise + f16 copy attnH (parked in dead Vp region)
//   gemm3_out : out = attnH @ Vt (plain f16)

typedef _Float16 half8 __attribute__((ext_vector_type(8)));
typedef float f32x16 __attribute__((ext_vector_type(16)));
typedef unsigned short u16;
typedef unsigned int u32;

#define BATCH 8
#define SEQ   2048
#define HID   1024
#define MINV  (-1e9f)

#define AS1 __attribute__((address_space(1)))
#define AS3 __attribute__((address_space(3)))

__device__ __forceinline__ u16 h2u(_Float16 h) { return __builtin_bit_cast(u16, h); }

__device__ __forceinline__ u32 packhl(float x) {
    _Float16 h = (_Float16)x;
    _Float16 l = (_Float16)(x - (float)h);
    return (u32)h2u(h) | ((u32)h2u(l) << 16);
}

__device__ __forceinline__ void gload16(const char* g, AS3 char* l) {
    __builtin_amdgcn_global_load_lds((const AS1 void*)g, (AS3 void*)l, 16, 0, 0);
}

// ---------------------------------------------------------------------------
__global__ __launch_bounds__(256) void prep_v(const float* __restrict__ V,
                                              u16* __restrict__ Vp,
                                              u16* __restrict__ Vt)
{
    __shared__ __align__(16) u16 lt[64 * 72];
    const int b = blockIdx.z, n0 = blockIdx.y * 64, h0 = blockIdx.x * 64;
    const int t = threadIdx.x;
    const int r = t >> 4, c4 = (t & 15) * 4;
#pragma unroll
    for (int it = 0; it < 4; ++it) {
        const int rr = r + it * 16;
        const float4 x = *(const float4*)(V + ((size_t)b * SEQ + n0 + rr) * HID + h0 + c4);
        const float xs[4] = {x.x, x.y, x.z, x.w};
        u32 p[4];
#pragma unroll
        for (int e = 0; e < 4; ++e) {
            p[e] = packhl(xs[e]);
            lt[(c4 + e) * 72 + rr] = (u16)p[e];
        }
        const int g = (h0 + c4) >> 5, j = c4 & 31;
        u16* base = Vp + (((size_t)b * SEQ + n0 + rr) * 32 + g) * 64;
        *(uint2*)(base + j) = make_uint2((p[0] & 0xffffu) | (p[1] << 16),
                                         (p[2] & 0xffffu) | (p[3] << 16));
        *(uint2*)(base + 32 + j) = make_uint2((p[0] >> 16) | (p[1] & 0xffff0000u),
                                              (p[2] >> 16) | (p[3] & 0xffff0000u));
    }
    __syncthreads();
    const int hr = t >> 2, cc = (t & 3) * 2;
    uint4 v0 = *(const uint4*)&lt[hr * 72 + cc * 8];
    uint4 v1 = *(const uint4*)&lt[hr * 72 + cc * 8 + 8];
    u16* dst = Vt + ((size_t)b * HID + h0 + hr) * SEQ + n0 + cc * 8;
    *(uint4*)dst = v0;
    *(uint4*)(dst + 8) = v1;
}

// ---------------------------------------------------------------------------
__global__ __launch_bounds__(256) void prep_w(const float* __restrict__ W,
                                              u16* __restrict__ Wtp)
{
    __shared__ __align__(16) u32 lt[64 * 68];
    const int n0 = blockIdx.x * 64, k0 = blockIdx.y * 64;
    const int t = threadIdx.x;
    const int r = t >> 4, c4 = (t & 15) * 4;
#pragma unroll
    for (int it = 0; it < 4; ++it) {
        const int rr = r + it * 16;
        const float4 x = *(const float4*)(W + (size_t)(k0 + rr) * HID + n0 + c4);
        const float xs[4] = {x.x, x.y, x.z, x.w};
#pragma unroll
        for (int e = 0; e < 4; ++e) lt[(c4 + e) * 68 + rr] = packhl(xs[e]);
    }
    __syncthreads();
    const int n = t >> 2;
#pragma unroll
    for (int s = 0; s < 4; ++s) {
        const int ci = (t & 3) + s * 4;
        uint4 v = *(const uint4*)&lt[n * 68 + ci * 4];
        const int k = k0 + ci * 4;
        u16* base = Wtp + (((size_t)n0 + n) * 32 + (k >> 5)) * 64;
        const int j = k & 31;
        *(uint2*)(base + j) = make_uint2((v.x & 0xffffu) | (v.y << 16),
                                         (v.z & 0xffffu) | (v.w << 16));
        *(uint2*)(base + 32 + j) = make_uint2((v.x >> 16) | (v.y & 0xffff0000u),
                                              (v.z >> 16) | (v.w & 0xffff0000u));
    }
}

// ---------------------------------------------------------------------------
__global__ __launch_bounds__(256) void prep_q(const float* __restrict__ Q,
                                              u16* __restrict__ Qp)
{
    const size_t row = blockIdx.x;
    const int t = threadIdx.x;
    const float4 x = ((const float4*)(Q + row * HID))[t];
    const u32 p0 = packhl(x.x), p1 = packhl(x.y), p2 = packhl(x.z), p3 = packhl(x.w);
    const int k = t * 4;
    u16* base = Qp + (row * 32 + (k >> 5)) * 64;
    const int j = k & 31;
    *(uint2*)(base + j) = make_uint2((p0 & 0xffffu) | (p1 << 16),
                                     (p2 & 0xffffu) | (p3 << 16));
    *(uint2*)(base + 32 + j) = make_uint2((p0 >> 16) | (p1 & 0xffff0000u),
                                          (p2 >> 16) | (p3 & 0xffff0000u));
}

// ---------------------------------------------------------------------------
// One 32x32 tile x one k-group (32 k split / 64 k plain).
// SPLIT frag index k: 0,1 = hi ksub0,1 ; 2,3 = lo ksub0,1.
// PLAIN frag index k = ksub 0..3.
// ---------------------------------------------------------------------------
template <bool SPLIT>
__device__ __forceinline__ void tilemm(f32x16& x, const half8 (&a)[4], const half8 (&b)[4])
{
    if constexpr (SPLIT) {
#pragma unroll
        for (int s = 0; s < 2; ++s) {
            x = __builtin_amdgcn_mfma_f32_32x32x16_f16(a[s + 2], b[s], x, 0, 0, 0);
            x = __builtin_amdgcn_mfma_f32_32x32x16_f16(a[s], b[s + 2], x, 0, 0, 0);
            x = __builtin_amdgcn_mfma_f32_32x32x16_f16(a[s], b[s], x, 0, 0, 0);
        }
    } else {
#pragma unroll
        for (int s = 0; s < 4; ++s)
            x = __builtin_amdgcn_mfma_f32_32x32x16_f16(a[s], b[s], x, 0, 0, 0);
    }
}

#define SBAR() __builtin_amdgcn_sched_barrier(0)

// ---------------------------------------------------------------------------
// One K-step. pa/pb: lane base ptrs into the CURRENT buffer (A/B row base);
// ko[4]: swizzled k-offsets kb16 ^ (k*32). ldsA/ldsB: NEXT-buffer staging.
// Phases: reads AH0(8)+B0(4) | gloads | reads B1(4) -> lgkm(4) QA ->
// lgkm(0) QB -> reads AH1(8, regs reused) -> lgkm(0) QC,QD ->
// vmcnt(0)+barrier (handled at next step's top).
// ---------------------------------------------------------------------------
template <int MODE>
__device__ __forceinline__ void kstep(
    const char* pa, const char* pb, const int (&ko)[4],
    AS3 char* ldsA, AS3 char* ldsB,
    const char* __restrict__ Ab, const char* __restrict__ Bb,
    const u32 (&aoffs)[4], const u32 (&boffs)[4], const int (&dsto)[4],
    u32 kb, bool more, f32x16 (&acc)[4][2])
{
    constexpr bool SPLIT = (MODE != 3);

    // single sync point: own gloads drained + all waves past last step's
    // reads -> current buffer resident, other buffer safe to overwrite.
    asm volatile("s_waitcnt vmcnt(0)" ::: "memory");
    __builtin_amdgcn_s_barrier();
    SBAR();

    half8 aF[2][4], bG[2][4];
#pragma unroll
    for (int t = 0; t < 2; ++t)
#pragma unroll
        for (int k = 0; k < 4; ++k)
            aF[t][k] = *(const half8*)(pa + t * 4096 + ko[k]);
#pragma unroll
    for (int k = 0; k < 4; ++k)
        bG[0][k] = *(const half8*)(pb + ko[k]);
    if (more) {
#pragma unroll
        for (int it = 0; it < 4; ++it) gload16(Ab + (aoffs[it] + kb), ldsA + dsto[it]);
#pragma unroll
        for (int it = 0; it < 4; ++it) gload16(Bb + (boffs[it] + kb), ldsB + dsto[it]);
    }
#pragma unroll
    for (int k = 0; k < 4; ++k)
        bG[1][k] = *(const half8*)(pb + 4096 + ko[k]);

    // QA: A-half0 x col0 (col1 reads drain underneath)
    asm volatile("s_waitcnt lgkmcnt(4)" ::: "memory");
    SBAR();
    __builtin_amdgcn_s_setprio(1);
    tilemm<SPLIT>(acc[0][0], aF[0], bG[0]);
    tilemm<SPLIT>(acc[1][0], aF[1], bG[0]);
    __builtin_amdgcn_s_setprio(0);

    // QB: A-half0 x col1
    asm volatile("s_waitcnt lgkmcnt(0)" ::: "memory");
    SBAR();
    __builtin_amdgcn_s_setprio(1);
    tilemm<SPLIT>(acc[0][1], aF[0], bG[1]);
    tilemm<SPLIT>(acc[1][1], aF[1], bG[1]);
    __builtin_amdgcn_s_setprio(0);

    // reads: A-half1 (regs reused — half0 dead)
#pragma unroll
    for (int t = 0; t < 2; ++t)
#pragma unroll
        for (int k = 0; k < 4; ++k)
            aF[t][k] = *(const half8*)(pa + 8192 + t * 4096 + ko[k]);

    // QC + QD: A-half1 x both cols (all regs)
    asm volatile("s_waitcnt lgkmcnt(0)" ::: "memory");
    SBAR();
    __builtin_amdgcn_s_setprio(1);
    tilemm<SPLIT>(acc[2][1], aF[0], bG[1]);
    tilemm<SPLIT>(acc[3][1], aF[1], bG[1]);
    tilemm<SPLIT>(acc[2][0], aF[0], bG[0]);
    tilemm<SPLIT>(acc[3][0], aF[1], bG[0]);
    __builtin_amdgcn_s_setprio(0);
    SBAR();
}

// ---------------------------------------------------------------------------
// GEMM body: 256x256 tile, 8 waves (2m x 4n), each wave 4x2 tiles of 32x32,
// double-buffered 128KB LDS, one vmcnt(0)+barrier per K-step, counted lgkm,
// K-loop unrolled x2 (compile-time buffer). XOR-swizzle (row&7)<<4 on both
// the staged global source and the ds_read offset (involution).
// MODE 1: split planes in, plane-grouped out; MODE 2: split planes,
// relu+mask, fp32 out; MODE 3: plain f16 (64 k/group), fp32 out.
// ---------------------------------------------------------------------------
template <int MODE>
__device__ __forceinline__ void gemm_body(
    char* smem,
    const char* __restrict__ Abase, const char* __restrict__ Bbase,
    void* __restrict__ Cbase, const int* __restrict__ Mbase,
    int ldc, long sAb, long sBb, long sC, long sM)
{
    // bijective XCD-aware block swizzle (all grids have nwg % 8 == 0)
    const int nx = gridDim.x, ny = gridDim.y;
    const int nxy = nx * ny;
    int wg = blockIdx.x + nx * (blockIdx.y + ny * blockIdx.z);
    const int cpx = (nxy * gridDim.z) >> 3;
    wg = (wg & 7) * cpx + (wg >> 3);
    const int bz = wg / nxy;
    const int rem = wg - bz * nxy;
    const int m0 = (rem / nx) * 256, n0 = (rem % nx) * 256;

    const int tid = threadIdx.x;
    const int w = tid >> 6, l = tid & 63;
    const int wm = w >> 2, wn = w & 3;            // 2 x 4 wave grid -> 128x64/wave
    const int l31 = l & 31, q2 = l >> 5;

    const char* Ab = Abase + (long)bz * sAb;
    const char* Bb = Bbase + (long)bz * sBb;

    // staging offsets (k-invariant): LDS slot -> inverse-swizzled global
    u32 aoffs[4], boffs[4];
    int dsto[4];
#pragma unroll
    for (int it = 0; it < 4; ++it) {
        const int off = it * 8192 + tid * 16;     // chunk it: rows [it*64, it*64+64)
        dsto[it] = off;
        const int row = off >> 7;
        const int swi = (off & 127) ^ ((row & 7) << 4);
        aoffs[it] = (u32)(m0 + row) * 4096u + (u32)swi;
        boffs[it] = (u32)(n0 + row) * 4096u + (u32)swi;
    }
    // swizzled k-offsets: frag k at natural byte (l>>5)*16 + k*32, XOR'd
    // with (row&7)<<4 = (l&7)<<4 (bit fields disjoint -> bitwise XOR valid)
    const int kb16 = (q2 << 4) ^ ((l & 7) << 4);
    int ko[4];
#pragma unroll
    for (int k = 0; k < 4; ++k) ko[k] = kb16 ^ (k << 5);

    f32x16 acc[4][2];
#pragma unroll
    for (int i = 0; i < 4; ++i)
#pragma unroll
        for (int j = 0; j < 2; ++j) acc[i][j] = (f32x16)(0.f);

    AS3 char* lds = (AS3 char*)smem;

    // prologue: stage K-step 0 into buf 0 (drained at loop top)
#pragma unroll
    for (int it = 0; it < 4; ++it) gload16(Ab + aoffs[it], lds + dsto[it]);
#pragma unroll
    for (int it = 0; it < 4; ++it) gload16(Bb + boffs[it], lds + 32768 + dsto[it]);

    // lane base pointers (A-row / B-row) per buffer
    const char* pa0 = smem + (wm * 128 + l31) * 128;
    const char* pb0 = smem + 32768 + (wn * 64 + l31) * 128;
    const char* pa1 = pa0 + 65536;
    const char* pb1 = pb0 + 65536;
    AS3 char* ldsA0 = lds;
    AS3 char* ldsB0 = lds + 32768;
    AS3 char* ldsA1 = lds + 65536;
    AS3 char* ldsB1 = lds + 65536 + 32768;

    for (int ks = 0; ks < 32; ks += 2) {
        kstep<MODE>(pa0, pb0, ko, ldsA1, ldsB1, Ab, Bb, aoffs, boffs, dsto,
                    (u32)(ks + 1) * 128u, true, acc);
        kstep<MODE>(pa1, pb1, ko, ldsA0, ldsB0, Ab, Bb, aoffs, boffs, dsto,
                    (u32)(ks + 2) * 128u, ks < 30, acc);
    }

    // ---- epilogue ----  32x32 C/D map: col = lane&31,
    // row = (r&3) + 8*(r>>2) + 4*(lane>>5), r = 0..15
#pragma unroll
    for (int ti = 0; ti < 4; ++ti) {
#pragma unroll
        for (int ci = 0; ci < 2; ++ci) {
            const int colbase = n0 + wn * 64 + ci * 32;
#pragma unroll
            for (int r = 0; r < 16; ++r) {
                const int row = (r & 3) + 8 * (r >> 2) + 4 * q2;
                const int grow = m0 + wm * 128 + ti * 32 + row;
                const int gcol = colbase + l31;
                const float v = acc[ti][ci][r];
                if constexpr (MODE == 1) {
                    const u32 p = packhl(v);
                    u16* base = (u16*)Cbase + ((size_t)grow * (ldc >> 5) + (colbase >> 5)) * 64;
                    base[l31] = (u16)p;
                    base[32 + l31] = (u16)(p >> 16);
                } else if constexpr (MODE == 2) {
                    const int mv = Mbase[(long)bz * sM + (long)grow * ldc + gcol];
                    ((float*)Cbase)[(long)bz * sC + (long)grow * ldc + gcol] =
                        (mv > 0) ? fmaxf(v, 0.f) : MINV;
                } else {
                    ((float*)Cbase)[(long)bz * sC + (long)grow * ldc + gcol] = v;
                }
            }
        }
    }
}

// distinct kernel names per mode (profiling visibility)
__global__ __launch_bounds__(512, 2) void gemm1_qw(
    const char* __restrict__ A, const char* __restrict__ B, void* __restrict__ C,
    const int* __restrict__ M, int ldc, long sAb, long sBb, long sC, long sM)
{
    extern __shared__ __align__(16) char smem[];
    gemm_body<1>(smem, A, B, C, M, ldc, sAb, sBb, sC, sM);
}
__global__ __launch_bounds__(512, 2) void gemm2_av(
    const char* __restrict__ A, const char* __restrict__ B, void* __restrict__ C,
    const int* __restrict__ M, int ldc, long sAb, long sBb, long sC, long sM)
{
    extern __shared__ __align__(16) char smem[];
    gemm_body<2>(smem, A, B, C, M, ldc, sAb, sBb, sC, sM);
}
__global__ __launch_bounds__(512, 2) void gemm3_out(
    const char* __restrict__ A, const char* __restrict__ B, void* __restrict__ C,
    const int* __restrict__ M, int ldc, long sAb, long sBb, long sC, long sM)
{
    extern __shared__ __align__(16) char smem[];
    gemm_body<3>(smem, A, B, C, M, ldc, sAb, sBb, sC, sM);
}

// ---------------------------------------------------------------------------
// Row softmax over 2048 elements, in place + f16 copy for gemm3.
// ---------------------------------------------------------------------------
__global__ __launch_bounds__(256) void softmax2048(float* __restrict__ attn,
                                                   u16* __restrict__ attnH)
{
    const long row = blockIdx.x;
    float* p = attn + row * 2048;
    const int tid = threadIdx.x;

    float4 v0 = ((const float4*)p)[tid];
    float4 v1 = ((const float4*)p)[tid + 256];

    float mx = fmaxf(fmaxf(fmaxf(v0.x, v0.y), fmaxf(v0.z, v0.w)),
                     fmaxf(fmaxf(v1.x, v1.y), fmaxf(v1.z, v1.w)));
#pragma unroll
    for (int o = 32; o >= 1; o >>= 1)
        mx = fmaxf(mx, __shfl_xor(mx, o, 64));

    __shared__ float redm[4];
    __shared__ float reds[4];
    const int wid = tid >> 6, lane = tid & 63;
    if (lane == 0) redm[wid] = mx;
    __syncthreads();
    mx = fmaxf(fmaxf(redm[0], redm[1]), fmaxf(redm[2], redm[3]));

    float e[8];
    e[0] = __expf(v0.x - mx); e[1] = __expf(v0.y - mx);
    e[2] = __expf(v0.z - mx); e[3] = __expf(v0.w - mx);
    e[4] = __expf(v1.x - mx); e[5] = __expf(v1.y - mx);
    e[6] = __expf(v1.z - mx); e[7] = __expf(v1.w - mx);

    float s = ((e[0] + e[1]) + (e[2] + e[3])) + ((e[4] + e[5]) + (e[6] + e[7]));
#pragma unroll
    for (int o = 32; o >= 1; o >>= 1)
        s += __shfl_xor(s, o, 64);
    if (lane == 0) reds[wid] = s;
    __syncthreads();
    s = (reds[0] + reds[1]) + (reds[2] + reds[3]);

    const float inv = 1.0f / s;
    float o0 = e[0] * inv, o1 = e[1] * inv, o2 = e[2] * inv, o3 = e[3] * inv;
    float o4 = e[4] * inv, o5 = e[5] * inv, o6 = e[6] * inv, o7 = e[7] * inv;
    ((float4*)p)[tid]       = make_float4(o0, o1, o2, o3);
    ((float4*)p)[tid + 256] = make_float4(o4, o5, o6, o7);

    u16* ph = attnH + row * 2048;
    ((uint2*)ph)[tid] =
        make_uint2((u32)h2u((_Float16)o0) | ((u32)h2u((_Float16)o1) << 16),
                   (u32)h2u((_Float16)o2) | ((u32)h2u((_Float16)o3) << 16));
    ((uint2*)ph)[tid + 256] =
        make_uint2((u32)h2u((_Float16)o4) | ((u32)h2u((_Float16)o5) << 16),
                   (u32)h2u((_Float16)o6) | ((u32)h2u((_Float16)o7) << 16));
}

extern "C" void kernel_launch(void* const* d_in, const int* in_sizes, int n_in,
                              void* d_out, int out_size, void* d_ws, size_t ws_size,
                              hipStream_t stream)
{
    (void)in_sizes; (void)n_in; (void)out_size; (void)ws_size;

    const float* query = (const float*)d_in[0];  // B,N,H
    const float* value = (const float*)d_in[1];  // B,N,H
    const int*   mask  = (const int*)d_in[2];    // B,N,N
    const float* W     = (const float*)d_in[3];  // H,H

    float* out  = (float*)d_out;                           // B*N*H
    float* attn = out + (size_t)BATCH * SEQ * HID;         // B*N*N

    // workspace: Vp 64MB | Vt 32MB | Wtp 4MB   (100MB total)
    u16* Vp  = (u16*)d_ws;
    u16* Vt  = (u16*)((char*)d_ws + ((size_t)64 << 20));
    u16* Wtp = (u16*)((char*)d_ws + ((size_t)96 << 20));

    // region reuse (stream-ordered, no overlap in time):
    u16* interP = (u16*)d_out;   // out region; dead once gemm3 writes out
    u16* Qp     = (u16*)attn;    // attn region; dead once gemm2 writes attn
    u16* attnH  = Vp;            // Vp region;  dead once gemm2 completes

    static int attr_done = 0;
    if (!attr_done) {
        hipFuncSetAttribute((const void*)gemm1_qw,
                            hipFuncAttributeMaxDynamicSharedMemorySize, 131072);
        hipFuncSetAttribute((const void*)gemm2_av,
                            hipFuncAttributeMaxDynamicSharedMemorySize, 131072);
        hipFuncSetAttribute((const void*)gemm3_out,
                            hipFuncAttributeMaxDynamicSharedMemorySize, 131072);
        attr_done = 1;
    }

    prep_v<<<dim3(HID / 64, SEQ / 64, BATCH), 256, 0, stream>>>(value, Vp, Vt);
    prep_w<<<dim3(HID / 64, HID / 64, 1), 256, 0, stream>>>(W, Wtp);
    prep_q<<<dim3(BATCH * SEQ), 256, 0, stream>>>(query, Qp);

    // gemm1: interP = split(Qp) @ Wtp^T   M=16384 N=1024 K=1024
    gemm1_qw<<<dim3(HID / 256, (BATCH * SEQ) / 256, 1), 512, 131072, stream>>>(
        (const char*)Qp, (const char*)Wtp, interP, nullptr,
        HID, 0, 0, 0, 0);

    // gemm2: logits = relu(interP @ Vp^T) masked -> attn (fp32)
    gemm2_av<<<dim3(SEQ / 256, SEQ / 256, BATCH), 512, 131072, stream>>>(
        (const char*)interP, (const char*)Vp, attn, mask,
        SEQ, (long)SEQ * 4096, (long)SEQ * 4096, (long)SEQ * SEQ, (long)SEQ * SEQ);

    softmax2048<<<dim3(BATCH * SEQ), 256, 0, stream>>>(attn, attnH);

    // gemm3: out = attnH @ Vt   M=2048 N=1024 K=2048 (plain f16, 64 k/group)
    gemm3_out<<<dim3(HID / 256, SEQ / 256, BATCH), 512, 131072, stream>>>(
        (const char*)attnH, (const char*)Vt, out, nullptr,
        HID, (long)SEQ * 4096, (long)HID * 4096, (long)SEQ * HID, 0);
}